// Round 9
// baseline (10154.861 us; speedup 1.0000x reference)
//
#include <hip/hip_runtime.h>

// HyperLSTM + MDN decoder — f32 in, f32 out.
// R15 = R14 with K2+K3 merged into ONE kernel (KB): 2 launches/step.
// KB blocks (bg 8-b group x sl 32 h-slice) recompute gate-sum + hh/ch + z
// for their 8 b's block-locally (redundant x32, deterministic; only sl==0
// writes state; ch parity-buffered to kill the write-after-read race).
// z stays in LDS (no g_z round-trip). Proj/MDN epilogue spread 31 items/block.
// No cross-block sync anywhere (R9/R12: device fences cost 35-90us on 8 XCDs).
#define MM     20
#define LATENT 128
#define IN_DIM 133
#define HD     1024
#define HD4    4096
#define HY     256
#define FF     64
#define NSEQ   128
#define BB     64
#define OUT_DIM 123   // 6*M+3

// Persistent state + intermediates (A-operands transposed: [k][b]).
__device__ float g_hT  [HD * BB];
__device__ float g_c   [BB * HD];
__device__ float g_chP [2][BB * HY];           // parity by step (t&1)
__device__ float g_hhT [HY * BB];
__device__ float g_xT  [NSEQ * 192 * BB];      // strokes^T, k-padded
__device__ float g_hWh [8][BB * HD4];          // h@Wh split-K partials (k=128)
__device__ float g_gH  [8][BB * HD];           // h-part of hyper gates
__device__ float g_ghh [2][BB * HD];           // hh@Whh_hy
__device__ float g_proj[8][BB * 128];          // proj split-K partials
__device__ float g_xWxA[NSEQ][BB * HD4];       // precomputed x@Wx
__device__ float g_gxA [NSEQ][BB * HD];        // precomputed x-part gates

__device__ __forceinline__ float sigf(float x) { return 1.0f / (1.0f + expf(-x)); }

__device__ __forceinline__ void gload_lds16(const float* g, float* l) {
    __builtin_amdgcn_global_load_lds(
        (const __attribute__((address_space(1))) void*)g,
        (__attribute__((address_space(3))) void*)l, 16, 0, 0);
}

// ---------------------------------------------------------------------------
// init: s0 = tanh(z @ fc_in_w + fc_in_b).  grid 64 x 256
// ---------------------------------------------------------------------------
__global__ __launch_bounds__(256) void init_kernel(
    const float* __restrict__ z, const float* __restrict__ fc_in_w,
    const float* __restrict__ fc_in_b)
{
    int b = blockIdx.x, tid = threadIdx.x;
    __shared__ float zs[LATENT];
    if (tid < LATENT) zs[tid] = z[b * LATENT + tid];
    __syncthreads();
    for (int j = tid; j < 2560; j += 256) {
        float acc = fc_in_b[j];
        #pragma unroll 4
        for (int k = 0; k < LATENT; k++) acc += zs[k] * fc_in_w[k * 2560 + j];
        float s = tanhf(acc);
        if      (j < 1024) g_hT [j * 64 + b]            = s;
        else if (j < 2048) g_c  [b * 1024 + (j - 1024)] = s;
        else if (j < 2304) g_hhT[(j - 2048) * 64 + b]   = s;
        else               g_chP[0][b * 256 + (j - 2304)] = s;
    }
}

__global__ __launch_bounds__(256) void xt_kernel(const float* __restrict__ strokes)
{
    int t = blockIdx.x, tid = threadIdx.x;
    for (int i = tid; i < 192 * 64; i += 256) {
        int k = i >> 6, b = i & 63;
        g_xT[t * 192 * 64 + i] =
            (k < IN_DIM) ? strokes[(t * BB + b) * IN_DIM + k] : 0.f;
    }
}

// ---- staging helpers: one 32k-row panel into dst ----
__device__ __forceinline__ void stage256(const float* Wp, int ldw, int wrows,
                                         int co, int pn, float* dst, int tid)
{
    #pragma unroll
    for (int q = 0; q < 4; q++) {
        int s = (q << 9) + tid;
        int r = s >> 6, c4 = s & 63;
        int kr = (pn << 5) + r; if (kr >= wrows) kr = wrows - 1;
        gload_lds16(Wp + kr * ldw + co + (c4 << 2), dst + (s << 2));
    }
}
__device__ __forceinline__ void stage128(const float* Wp, int ldw, int wrows,
                                         int co, int pn, bool wS, float* dst, int tid)
{
    if (!wS) {
        #pragma unroll
        for (int q = 0; q < 2; q++) {
            int s = (q << 9) + tid;
            int r = s >> 5, c4 = s & 31;
            int kr = (pn << 5) + r; if (kr >= wrows) kr = wrows - 1;
            gload_lds16(Wp + kr * ldw + co + (c4 << 2), dst + (s << 2));
        }
    } else {
        #pragma unroll
        for (int q = 0; q < 8; q++) {
            int idx = (q << 9) + tid;
            int r = idx >> 7, c = idx & 127;
            int kr = (pn << 5) + r; if (kr >= wrows) kr = wrows - 1;
            dst[idx] = (c < OUT_DIM) ? Wp[kr * ldw + c] : 0.f;
        }
    }
}

// 64b x 256c tile, np panels of 32 k. 512 thr: 8b x 4c. LDS 2x32KB dbuf.
__device__ __forceinline__ void gemm256(
    const float* AT, const float* Wp, int ldw, int wrows, int co, int np,
    float* Op, int ldo, float* pool, int tid)
{
    int cq = tid & 63, bq = tid >> 6;
    float4 acc0 = {0,0,0,0}, acc1 = {0,0,0,0}, acc2 = {0,0,0,0}, acc3 = {0,0,0,0};
    float4 acc4 = {0,0,0,0}, acc5 = {0,0,0,0}, acc6 = {0,0,0,0}, acc7 = {0,0,0,0};
    stage256(Wp, ldw, wrows, co, 0, pool, tid);
    for (int pn = 0; pn < np; pn++) {
        __syncthreads();
        if (pn + 1 < np)
            stage256(Wp, ldw, wrows, co, pn + 1,
                     pool + (((pn + 1) & 1) << 13), tid);
        const float* Ap2 = AT + (pn << 11) + (bq << 3);
        const float* Wcc = pool + ((pn & 1) << 13) + (cq << 2);
        #pragma unroll 8
        for (int k = 0; k < 32; k++) {
            float4 a0 = *(const float4*)(Ap2 + (k << 6));
            float4 a1 = *(const float4*)(Ap2 + (k << 6) + 4);
            float4 w  = *(const float4*)(Wcc + (k << 8));
            acc0.x += a0.x*w.x; acc0.y += a0.x*w.y; acc0.z += a0.x*w.z; acc0.w += a0.x*w.w;
            acc1.x += a0.y*w.x; acc1.y += a0.y*w.y; acc1.z += a0.y*w.z; acc1.w += a0.y*w.w;
            acc2.x += a0.z*w.x; acc2.y += a0.z*w.y; acc2.z += a0.z*w.z; acc2.w += a0.z*w.w;
            acc3.x += a0.w*w.x; acc3.y += a0.w*w.y; acc3.z += a0.w*w.z; acc3.w += a0.w*w.w;
            acc4.x += a1.x*w.x; acc4.y += a1.x*w.y; acc4.z += a1.x*w.z; acc4.w += a1.x*w.w;
            acc5.x += a1.y*w.x; acc5.y += a1.y*w.y; acc5.z += a1.y*w.z; acc5.w += a1.y*w.w;
            acc6.x += a1.z*w.x; acc6.y += a1.z*w.y; acc6.z += a1.z*w.z; acc6.w += a1.z*w.w;
            acc7.x += a1.w*w.x; acc7.y += a1.w*w.y; acc7.z += a1.w*w.z; acc7.w += a1.w*w.w;
        }
    }
    float* op = Op + (bq << 3) * ldo + co + (cq << 2);
    *(float4*)(op)           = acc0;  *(float4*)(op + ldo)     = acc1;
    *(float4*)(op + 2 * ldo) = acc2;  *(float4*)(op + 3 * ldo) = acc3;
    *(float4*)(op + 4 * ldo) = acc4;  *(float4*)(op + 5 * ldo) = acc5;
    *(float4*)(op + 6 * ldo) = acc6;  *(float4*)(op + 7 * ldo) = acc7;
}

// 64b x 128c tile, np panels of 32 k. 512 thr: 4b x 4c. LDS 2x16KB dbuf.
__device__ __forceinline__ void gemm128(
    const float* AT, const float* Wp, int ldw, int wrows, int co, int np,
    bool wS, float* Op, int ldo, float* pool, int tid)
{
    int cq = tid & 31, bq = tid >> 5;
    float4 acc0 = {0,0,0,0}, acc1 = {0,0,0,0}, acc2 = {0,0,0,0}, acc3 = {0,0,0,0};
    stage128(Wp, ldw, wrows, co, 0, wS, pool, tid);
    for (int pn = 0; pn < np; pn++) {
        __syncthreads();
        if (pn + 1 < np)
            stage128(Wp, ldw, wrows, co, pn + 1, wS,
                     pool + (((pn + 1) & 1) << 12), tid);
        const float* Ap2 = AT + (pn << 11) + (bq << 2);
        const float* Wcc = pool + ((pn & 1) << 12) + (cq << 2);
        #pragma unroll 8
        for (int k = 0; k < 32; k++) {
            float4 a = *(const float4*)(Ap2 + (k << 6));
            float4 w = *(const float4*)(Wcc + (k << 7));
            acc0.x += a.x*w.x; acc0.y += a.x*w.y; acc0.z += a.x*w.z; acc0.w += a.x*w.w;
            acc1.x += a.y*w.x; acc1.y += a.y*w.y; acc1.z += a.y*w.z; acc1.w += a.y*w.w;
            acc2.x += a.z*w.x; acc2.y += a.z*w.y; acc2.z += a.z*w.z; acc2.w += a.z*w.w;
            acc3.x += a.w*w.x; acc3.y += a.w*w.y; acc3.z += a.w*w.z; acc3.w += a.w*w.w;
        }
    }
    float* op = Op + (bq << 2) * ldo + co + (cq << 2);
    *(float4*)(op)           = acc0;  *(float4*)(op + ldo)     = acc1;
    *(float4*)(op + 2 * ldo) = acc2;  *(float4*)(op + 3 * ldo) = acc3;
}

// ---------------------------------------------------------------------------
// pre: one-time batched x-GEMMs for ALL t. grid 5120 x 512.
// ---------------------------------------------------------------------------
__global__ __launch_bounds__(512, 2) void pre_kernel(
    const float* __restrict__ Wx, const float* __restrict__ Wxh_hy)
{
    __shared__ float pool[8192];
    int u = blockIdx.x, tid = threadIdx.x;
    if (u < 4096) {
        int t = u >> 5, ct = u & 31;
        gemm128(g_xT + t * 192 * 64, Wx, HD4, IN_DIM, ct * 128, 5, false,
                g_xWxA[t], HD4, pool, tid);
    } else {
        int i = u - 4096, t = i >> 3, ct = i & 7;
        gemm128(g_xT + t * 192 * 64, Wxh_hy, HD, IN_DIM, ct * 128, 5, false,
                g_gxA[t], HD, pool, tid);
    }
}

// ---------------------------------------------------------------------------
// KA: recurrent tile GEMMs. grid 176 x 512 (k-chunk=128, np=4 panels of 32):
//   [0,128) hWh 8ch x 16ct (256c)  [128,160) gH 8ch x 4ct  [160,168) ghh
//   [168,176) proj 8ch (128c).  Tail (t==NSEQ): proj only.
// ---------------------------------------------------------------------------
__global__ __launch_bounds__(512, 2) void ka_kernel(
    const float* __restrict__ Wh, const float* __restrict__ Wxh_hy,
    const float* __restrict__ Whh_hy, const float* __restrict__ fc_proj_w, int t)
{
    __shared__ float pool[16384];
    int u = blockIdx.x, tid = threadIdx.x;
    if (u < 128) {
        if (t < NSEQ) {
            int ch = u >> 4, ct = u & 15;
            gemm256(g_hT + ch * 128 * 64, Wh + ch * 128 * HD4,
                    HD4, 128, ct * 256, 4, g_hWh[ch], HD4, pool, tid);
        }
    } else if (u < 160) {
        if (t < NSEQ) {
            int i = u - 128, ch = i >> 2, ct = i & 3;
            gemm256(g_hT + ch * 128 * 64, Wxh_hy + (133 + ch * 128) * HD,
                    HD, 128, ct * 256, 4, g_gH[ch], HD, pool, tid);
        }
    } else if (u < 168) {
        if (t < NSEQ) {
            int i = u - 160, ch = i >> 2, ct = i & 3;
            gemm256(g_hhT + ch * 128 * 64, Whh_hy + ch * 128 * HD,
                    HD, 128, ct * 256, 4, g_ghh[ch], HD, pool, tid);
        }
    } else {
        if (t > 0) {
            int ch = u - 168;
            gemm128(g_hT + ch * 128 * 64, fc_proj_w + ch * 128 * OUT_DIM,
                    OUT_DIM, 128, 0, 4, true, g_proj[ch], 128, pool, tid);
        }
    }
}

// ---------------------------------------------------------------------------
// KB: merged K2+K3. grid 256 (bg = blk>>5: 8 b's; sl = blk&31: 32 hi-slice).
// Per block: gate-sum(8b) -> hh/ch (parity; sl==0 writes) -> z(8b, LDS) ->
// einsum + combine + LSTM update. Epilogue: 31 proj/MDN items per block.
// ---------------------------------------------------------------------------
__global__ __launch_bounds__(512) void kb_kernel(
    const float* __restrict__ b_hy,
    const float* __restrict__ Wzx, const float* __restrict__ bzx,
    const float* __restrict__ Wzh, const float* __restrict__ bzh,
    const float* __restrict__ Wzb,
    const float* __restrict__ Dx, const float* __restrict__ Dh,
    const float* __restrict__ Db, const float* __restrict__ b0w,
    const float* __restrict__ fc_proj_b, float* __restrict__ out, int t)
{
    __shared__ float pool[11264];     // 44 KB
    float* gsum = pool;               // 8 x 1024 (phase 1-2)
    float* zC   = pool;               // 8 x 768  (reuses gsum, phase 3+)
    float* hhL  = pool + 8192;        // 8 x 256
    float* preC = pool + 10240;       // 1024
    int blk = blockIdx.x, tid = threadIdx.x;
    int bg = blk >> 5, sl = blk & 31;

    if (t < NSEQ) {
        int par = t & 1;
        // ---- phase 1: gate-sum for this block's 8 b ----
        #pragma unroll
        for (int p = 0; p < 4; p++) {
            int q = (p << 9) + tid;                 // 0..2047 float4-quads
            int b = q >> 8, j4 = (q & 255) << 2;
            int base = ((bg << 3) + b) * HD + j4;
            float4 a = *(const float4*)(b_hy + j4);
            float4 v = *(const float4*)(&g_gxA[t][base]);
            a.x += v.x; a.y += v.y; a.z += v.z; a.w += v.w;
            #pragma unroll
            for (int c = 0; c < 8; c++) {
                float4 u = *(const float4*)(&g_gH[c][base]);
                a.x += u.x; a.y += u.y; a.z += u.z; a.w += u.w;
            }
            float4 u0 = *(const float4*)(&g_ghh[0][base]);
            a.x += u0.x; a.y += u0.y; a.z += u0.z; a.w += u0.w;
            float4 u1 = *(const float4*)(&g_ghh[1][base]);
            a.x += u1.x; a.y += u1.y; a.z += u1.z; a.w += u1.w;
            *(float4*)(&gsum[(b << 10) + j4]) = a;
        }
        __syncthreads();
        // ---- phase 2: hh/ch update (all blocks compute; sl==0 writes) ----
        #pragma unroll
        for (int p = 0; p < 2; p++) {
            int e = (p << 9) + tid;                 // 0..1023? need 2048
            // handle two elems per iteration to cover 2048
            #pragma unroll
            for (int h2 = 0; h2 < 2; h2++) {
                int ee = e + (h2 << 10);
                int b = ee >> 8, j = ee & 255;
                int row = b << 10;
                float gi = gsum[row + j],       gf = gsum[row + 256 + j];
                float gg = gsum[row + 512 + j], go = gsum[row + 768 + j];
                int b8 = (bg << 3) + b;
                float ch = g_chP[par][(b8 << 8) + j];
                ch = sigf(gf) * ch + sigf(gi) * tanhf(gg);
                float hh = sigf(go) * tanhf(ch);
                hhL[(b << 8) + j] = hh;
                if (sl == 0) {
                    g_chP[par ^ 1][(b8 << 8) + j] = ch;
                    g_hhT[(j << 6) + b8] = hh;
                }
            }
        }
        __syncthreads();
        // ---- phase 3: z for 8 b (into zC, overwrites gsum region) ----
        {
            int oo = tid & 255, half = tid >> 8;
            const float* h0 = hhL + ((half << 2) << 8);
            float bx = bzx[oo], bh = bzh[oo];
            float x0=bx,x1=bx,x2=bx,x3=bx;
            float y0=bh,y1=bh,y2=bh,y3=bh;
            float v0=0.f,v1=0.f,v2=0.f,v3=0.f;
            #pragma unroll 4
            for (int k = 0; k < 256; k++) {
                float wx = Wzx[(k << 8) + oo];
                float wh = Wzh[(k << 8) + oo];
                float wb = Wzb[(k << 8) + oo];
                float ha = h0[k], hb = h0[256 + k], hc = h0[512 + k], hd = h0[768 + k];
                x0 += ha*wx; x1 += hb*wx; x2 += hc*wx; x3 += hd*wx;
                y0 += ha*wh; y1 += hb*wh; y2 += hc*wh; y3 += hd*wh;
                v0 += ha*wb; v1 += hb*wb; v2 += hc*wb; v3 += hd*wb;
            }
            int zb = ((half << 2) * 768) + oo;
            zC[zb]        = x0; zC[zb + 768]  = x1;
            zC[zb + 1536] = x2; zC[zb + 2304] = x3;
            zC[zb + 256]        = y0; zC[zb + 256 + 768]  = y1;
            zC[zb + 256 + 1536] = y2; zC[zb + 256 + 2304] = y3;
            zC[zb + 512]        = v0; zC[zb + 512 + 768]  = v1;
            zC[zb + 512 + 1536] = v2; zC[zb + 512 + 2304] = v3;
        }
        __syncthreads();
        // ---- phase 4: einsum + combine partials ----
        {
            int hi0 = sl << 5;
            int hi_l = tid & 31, gq = (tid >> 5) & 3, b4 = tid >> 7;
            int hi = hi0 + hi_l;
            const float* dxp = Dx + gq * 64 * HD + hi;
            const float* dhp = Dh + gq * 64 * HD + hi;
            const float* dbp = Db + gq * 64 * HD + hi;
            const float* z0 = zC + b4 * 768;
            const float* z1 = zC + (b4 + 4) * 768;
            int zo = gq << 6;
            float ax0=0.f, ah0=0.f, ab0=0.f, ax1=0.f, ah1=0.f, ab1=0.f;
            #pragma unroll 4
            for (int f = 0; f < FF; f++) {
                float dx = dxp[f * HD], dh = dhp[f * HD], db = dbp[f * HD];
                ax0 += z0[zo + f] * dx; ah0 += z0[256 + zo + f] * dh;
                ab0 += z0[512 + zo + f] * db;
                ax1 += z1[zo + f] * dx; ah1 += z1[256 + zo + f] * dh;
                ab1 += z1[512 + zo + f] * db;
            }
            int idx = (gq << 10) + hi;
            int b0i = (bg << 3) + b4, b1i = b0i + 4;
            float hw0 = 0.f, hw1 = 0.f;
            #pragma unroll
            for (int q = 0; q < 8; q++) {
                hw0 += g_hWh[q][b0i * HD4 + idx];
                hw1 += g_hWh[q][b1i * HD4 + idx];
            }
            float xw0 = g_xWxA[t][b0i * HD4 + idx];
            float xw1 = g_xWxA[t][b1i * HD4 + idx];
            float bw = b0w[idx];
            float pre0 = ax0 * xw0 + ah0 * hw0 + ab0 + bw;
            float pre1 = ax1 * xw1 + ah1 * hw1 + ab1 + bw;
            preC[((b4 << 2) + gq) * 32 + hi_l]       = pre0;
            preC[(((b4 + 4) << 2) + gq) * 32 + hi_l] = pre1;
        }
        __syncthreads();
        // ---- phase 5: main LSTM update ----
        if (tid < 256) {
            int hi0 = sl << 5;
            int bi = tid >> 5, hl = tid & 31;
            int b8 = (bg << 3) + bi, ha = b8 * HD + hi0 + hl;
            float pi = preC[((bi << 2) + 0) * 32 + hl];
            float pf = preC[((bi << 2) + 1) * 32 + hl];
            float pg = preC[((bi << 2) + 2) * 32 + hl];
            float po = preC[((bi << 2) + 3) * 32 + hl];
            float cv = g_c[ha];
            float nc = sigf(pf) * cv + sigf(pi) * tanhf(pg);
            float nh = sigf(po) * tanhf(nc);
            g_c[ha] = nc;
            g_hT[(hi0 + hl) * 64 + b8] = nh;
        }
    }
    // ---- epilogue: proj + MDN for tp = t-1 (31 items per block) ----
    if (t > 0 && tid < 31) {
        int i = blk * 31 + tid;                    // 0..7935 = 64 b x 124 c
        int b = i / 124, c = i - b * 124;
        int tp = t - 1, base7 = b << 7;
        if (c < 120) {
            float v = fc_proj_b[c];
            #pragma unroll
            for (int q = 0; q < 8; q++) v += g_proj[q][base7 + c];
            int m = c / 6, r = c - m * 6;
            int oidx = tp * (MM * BB) + m * BB + b;
            if      (r == 0) out[oidx]          = 1.0f;   // size-1 softmax
            else if (r == 1) out[163840 + oidx] = v;
            else if (r == 2) out[327680 + oidx] = v;
            else if (r == 3) out[491520 + oidx] = expf(v);
            else if (r == 4) out[655360 + oidx] = expf(v);
            else             out[819200 + oidx] = tanhf(v);
        } else if (c == 120) {                     // pen-state softmax
            float p0 = fc_proj_b[120], p1 = fc_proj_b[121], p2 = fc_proj_b[122];
            #pragma unroll
            for (int q = 0; q < 8; q++) {
                p0 += g_proj[q][base7 + 120];
                p1 += g_proj[q][base7 + 121];
                p2 += g_proj[q][base7 + 122];
            }
            float mx = fmaxf(p0, fmaxf(p1, p2));
            float e0 = expf(p0 - mx), e1 = expf(p1 - mx), e2 = expf(p2 - mx);
            float s = e0 + e1 + e2;
            int ob = 983040 + tp * (BB * 3) + b * 3;
            out[ob + 0] = e0 / s; out[ob + 1] = e1 / s; out[ob + 2] = e2 / s;
        }
    }
}

// ---------------------------------------------------------------------------
extern "C" void kernel_launch(void* const* d_in, const int* in_sizes, int n_in,
                              void* d_out, int out_size, void* d_ws, size_t ws_size,
                              hipStream_t stream)
{
    const float* z         = (const float*)d_in[0];
    const float* strokes   = (const float*)d_in[1];
    const float* fc_in_w   = (const float*)d_in[2];
    const float* fc_in_b   = (const float*)d_in[3];
    const float* fc_proj_w = (const float*)d_in[4];
    const float* fc_proj_b = (const float*)d_in[5];
    const float* Wx        = (const float*)d_in[6];
    const float* Wh        = (const float*)d_in[7];
    const float* b0w       = (const float*)d_in[8];
    const float* Wxh_hy    = (const float*)d_in[9];
    const float* Whh_hy    = (const float*)d_in[10];
    const float* b_hy      = (const float*)d_in[11];
    const float* Wzx       = (const float*)d_in[12];
    const float* bzx       = (const float*)d_in[13];
    const float* Wzh       = (const float*)d_in[14];
    const float* bzh       = (const float*)d_in[15];
    const float* Wzb       = (const float*)d_in[16];
    const float* Dx        = (const float*)d_in[17];
    const float* Dh        = (const float*)d_in[18];
    const float* Db        = (const float*)d_in[19];
    (void)d_ws; (void)ws_size; (void)in_sizes; (void)n_in; (void)out_size;
    float* out = (float*)d_out;

    init_kernel<<<64, 256, 0, stream>>>(z, fc_in_w, fc_in_b);
    xt_kernel<<<128, 256, 0, stream>>>(strokes);
    pre_kernel<<<5120, 512, 0, stream>>>(Wx, Wxh_hy);
    for (int t = 0; t < NSEQ; t++) {
        ka_kernel<<<176, 512, 0, stream>>>(Wh, Wxh_hy, Whh_hy, fc_proj_w, t);
        kb_kernel<<<256, 512, 0, stream>>>(b_hy, Wzx, bzx, Wzh, bzh, Wzb,
                                           Dx, Dh, Db, b0w, fc_proj_b, out, t);
    }
    // tail: proj of h_127 + its epilogue
    ka_kernel<<<176, 512, 0, stream>>>(Wh, Wxh_hy, Whh_hy, fc_proj_w, NSEQ);
    kb_kernel<<<256, 512, 0, stream>>>(b_hy, Wzx, bzx, Wzh, bzh, Wzb,
                                       Dx, Dh, Db, b0w, fc_proj_b, out, NSEQ);
}

// Round 10
// 5989.780 us; speedup vs baseline: 1.6954x; 1.6954x over previous
//
#include <hip/hip_runtime.h>

// HyperLSTM + MDN decoder — f32 in, f32 out.
// R16 = R14 skeleton with the recurrent GEMMs (hWh, gH, ghh, proj) moved to
// bf16x3 MFMA (v_mfma_f32_16x16x32_bf16, hi/lo split -> ~f32 precision).
// Weights pre-packed ONCE into fragment-major bf16 hi/lo arrays; h/hh stored
// as bf16 hi/lo rows by K3/K2/init. KA uses no LDS. K-permutation of the
// fragment layout cancels because A and B are packed with the same slot map.
#define MM     20
#define LATENT 128
#define IN_DIM 133
#define HD     1024
#define HD4    4096
#define HY     256
#define FF     64
#define NSEQ   128
#define BB     64
#define OUT_DIM 123   // 6*M+3

typedef __attribute__((ext_vector_type(8))) short short8v;   // 8 bf16
typedef __attribute__((ext_vector_type(4))) float f32x4v;

// ---- persistent state / intermediates ----
__device__ float  g_c    [BB * HD];
__device__ float  g_ch   [BB * HY];
__device__ float  g_xT   [NSEQ * 192 * BB];     // strokes^T (pre only)
__device__ float  g_hWh  [8][BB * HD4];         // h@Wh split-K partials (k=128)
__device__ float  g_gH   [8][BB * HD];
__device__ float  g_ghh  [2][BB * HD];
__device__ float  g_z    [BB * 3 * HY];
__device__ float  g_proj [8][BB * 128];
__device__ float  g_xWxA [NSEQ][BB * HD4];      // precomputed x@Wx
__device__ float  g_gxA  [NSEQ][BB * HD];       // precomputed x-part gates
// bf16 hi/lo operand rows (A of MFMA): [b][k]
__device__ unsigned short g_hRowHi [BB * HD],  g_hRowLo [BB * HD];
__device__ unsigned short g_hhRowHi[BB * HY],  g_hhRowLo[BB * HY];
// packed weights, fragment-major: [s][n][lane][8] bf16
__device__ unsigned short pkWhHi[32 * 256 * 512], pkWhLo[32 * 256 * 512];
__device__ unsigned short pkGhHi[32 *  64 * 512], pkGhLo[32 *  64 * 512];
__device__ unsigned short pkHhHi[ 8 *  64 * 512], pkHhLo[ 8 *  64 * 512];
__device__ unsigned short pkPjHi[32 *   8 * 512], pkPjLo[32 *   8 * 512];

__device__ __forceinline__ float sigf(float x) { return 1.0f / (1.0f + expf(-x)); }

__device__ __forceinline__ unsigned short bf16hi(float x) {
    union { float f; unsigned u; } v; v.f = x;
    unsigned r = v.u + 0x7FFFu + ((v.u >> 16) & 1u);
    return (unsigned short)(r >> 16);
}
__device__ __forceinline__ float bf16f(unsigned short h) {
    union { unsigned u; float f; } v; v.u = ((unsigned)h) << 16;
    return v.f;
}
__device__ __forceinline__ void bf16pair(float x, unsigned short* hi, unsigned short* lo) {
    unsigned short h = bf16hi(x);
    *hi = h;
    *lo = bf16hi(x - bf16f(h));
}

__device__ __forceinline__ void gload_lds16(const float* g, float* l) {
    __builtin_amdgcn_global_load_lds(
        (const __attribute__((address_space(1))) void*)g,
        (__attribute__((address_space(3))) void*)l, 16, 0, 0);
}

// ---------------------------------------------------------------------------
// init: s0 = tanh(z @ fc_in_w + fc_in_b).  grid 64 x 256
// ---------------------------------------------------------------------------
__global__ __launch_bounds__(256) void init_kernel(
    const float* __restrict__ z, const float* __restrict__ fc_in_w,
    const float* __restrict__ fc_in_b)
{
    int b = blockIdx.x, tid = threadIdx.x;
    __shared__ float zs[LATENT];
    if (tid < LATENT) zs[tid] = z[b * LATENT + tid];
    __syncthreads();
    for (int j = tid; j < 2560; j += 256) {
        float acc = fc_in_b[j];
        #pragma unroll 4
        for (int k = 0; k < LATENT; k++) acc += zs[k] * fc_in_w[k * 2560 + j];
        float s = tanhf(acc);
        if (j < 1024) {
            bf16pair(s, &g_hRowHi[b * HD + j], &g_hRowLo[b * HD + j]);
        } else if (j < 2048) {
            g_c[b * 1024 + (j - 1024)] = s;
        } else if (j < 2304) {
            int jj = j - 2048;
            bf16pair(s, &g_hhRowHi[b * HY + jj], &g_hhRowLo[b * HY + jj]);
        } else {
            g_ch[b * 256 + (j - 2304)] = s;
        }
    }
}

__global__ __launch_bounds__(256) void xt_kernel(const float* __restrict__ strokes)
{
    int t = blockIdx.x, tid = threadIdx.x;
    for (int i = tid; i < 192 * 64; i += 256) {
        int k = i >> 6, b = i & 63;
        g_xT[t * 192 * 64 + i] =
            (k < IN_DIM) ? strokes[(t * BB + b) * IN_DIM + k] : 0.f;
    }
}

// ---------------------------------------------------------------------------
// pack: weights -> fragment-major bf16 hi/lo. One block per fragment (512 thr,
// thread = elem): slot (lane = tid>>3, j = tid&7) <-> W[k][c] with
// k = s*32 + (lane>>4)*8 + j, c = n*16 + (lane&15). Same map as A loads.
// grid 11008: [0,8192) Wh | [8192,10240) gH | [10240,10752) ghh | rest proj.
// ---------------------------------------------------------------------------
__global__ __launch_bounds__(512) void pack_kernel(
    const float* __restrict__ Wh, const float* __restrict__ Wxh_hy,
    const float* __restrict__ Whh_hy, const float* __restrict__ fc_proj_w)
{
    int f = blockIdx.x, tid = threadIdx.x;
    int l = tid >> 3, j = tid & 7;
    int kk = ((l >> 4) << 3) + j, cc = l & 15;
    float val; unsigned short *hi, *lo;
    if (f < 8192) {
        int s = f >> 8, n = f & 255;
        val = Wh[(s * 32 + kk) * HD4 + n * 16 + cc];
        hi = &pkWhHi[f * 512 + tid]; lo = &pkWhLo[f * 512 + tid];
    } else if (f < 10240) {
        int f2 = f - 8192, s = f2 >> 6, n = f2 & 63;
        val = Wxh_hy[(133 + s * 32 + kk) * HD + n * 16 + cc];
        hi = &pkGhHi[f2 * 512 + tid]; lo = &pkGhLo[f2 * 512 + tid];
    } else if (f < 10752) {
        int f2 = f - 10240, s = f2 >> 6, n = f2 & 63;
        val = Whh_hy[(s * 32 + kk) * HD + n * 16 + cc];
        hi = &pkHhHi[f2 * 512 + tid]; lo = &pkHhLo[f2 * 512 + tid];
    } else {
        int f2 = f - 10752, s = f2 >> 3, n = f2 & 7;
        int c = n * 16 + cc;
        val = (c < OUT_DIM) ? fc_proj_w[(s * 32 + kk) * OUT_DIM + c] : 0.f;
        hi = &pkPjHi[f2 * 512 + tid]; lo = &pkPjLo[f2 * 512 + tid];
    }
    bf16pair(val, hi, lo);
}

// ---------------------------------------------------------------------------
// MFMA tile GEMM: 64b x (NT*16)c, k = NS*32 starting slice s0. 512 thr =
// 8 waves: wave w -> M-tile (w&3), n-half (w>>2) of NTW tiles. bf16x3.
// ---------------------------------------------------------------------------
template<int NTW>
__device__ __forceinline__ void mfma_gemm(
    const unsigned short* __restrict__ aHi, const unsigned short* __restrict__ aLo,
    int lda,
    const unsigned short* __restrict__ pHi, const unsigned short* __restrict__ pLo,
    int ntTot, int s0, int ns, int n0,
    float* __restrict__ Op, int ldo, int tid)
{
    int w = tid >> 6, l = tid & 63;
    int mt = w & 3, nh = w >> 2;
    int b0 = (mt << 4) + (l & 15);
    int kj = (l >> 4) << 3;
    f32x4v acc[NTW];
    #pragma unroll
    for (int i = 0; i < NTW; i++) acc[i] = (f32x4v){0.f, 0.f, 0.f, 0.f};
    for (int s = 0; s < ns; s++) {
        int sg = s0 + s;
        int koff = (sg << 5) + kj;
        short8v ah = *(const short8v*)(aHi + b0 * lda + koff);
        short8v al = *(const short8v*)(aLo + b0 * lda + koff);
        long fb = ((long)(sg * ntTot + n0 + nh * NTW) << 9) + (l << 3);
        #pragma unroll
        for (int nt = 0; nt < NTW; nt++) {
            short8v bh = *(const short8v*)(pHi + fb + (nt << 9));
            short8v bl = *(const short8v*)(pLo + fb + (nt << 9));
            acc[nt] = __builtin_amdgcn_mfma_f32_16x16x32_bf16(ah, bh, acc[nt], 0, 0, 0);
            acc[nt] = __builtin_amdgcn_mfma_f32_16x16x32_bf16(al, bh, acc[nt], 0, 0, 0);
            acc[nt] = __builtin_amdgcn_mfma_f32_16x16x32_bf16(ah, bl, acc[nt], 0, 0, 0);
        }
    }
    // C/D layout (m89-verified): col = lane&15, row = (lane>>4)*4 + j
    int rb = (mt << 4) + ((l >> 4) << 2);
    int cb = (n0 + nh * NTW) * 16 + (l & 15);
    #pragma unroll
    for (int nt = 0; nt < NTW; nt++) {
        #pragma unroll
        for (int j = 0; j < 4; j++)
            Op[(rb + j) * ldo + cb + (nt << 4)] = acc[nt][j];
    }
}

// ---------------------------------------------------------------------------
// KA: recurrent GEMMs, all MFMA. grid 176 x 512, no LDS.
//   [0,128)   hWh  8ch x 16ct (256c)   [128,160) gH 8ch x 4ct (256c)
//   [160,168) ghh  2ch x 4ct (256c)    [168,176) proj 8ch (128c)
// Tail (t==NSEQ): proj only.
// ---------------------------------------------------------------------------
__global__ __launch_bounds__(512) void ka_kernel(int t)
{
    int u = blockIdx.x, tid = threadIdx.x;
    if (u < 128) {
        if (t < NSEQ) {
            int ch = u >> 4, ct = u & 15;
            mfma_gemm<8>(g_hRowHi, g_hRowLo, HD, pkWhHi, pkWhLo, 256,
                         ch * 4, 4, ct * 16, g_hWh[ch], HD4, tid);
        }
    } else if (u < 160) {
        if (t < NSEQ) {
            int i = u - 128, ch = i >> 2, ct = i & 3;
            mfma_gemm<8>(g_hRowHi, g_hRowLo, HD, pkGhHi, pkGhLo, 64,
                         ch * 4, 4, ct * 16, g_gH[ch], HD, tid);
        }
    } else if (u < 168) {
        if (t < NSEQ) {
            int i = u - 160, ch = i >> 2, ct = i & 3;
            mfma_gemm<8>(g_hhRowHi, g_hhRowLo, HY, pkHhHi, pkHhLo, 64,
                         ch * 4, 4, ct * 16, g_ghh[ch], HD, tid);
        }
    } else {
        if (t > 0) {
            int ch = u - 168;
            mfma_gemm<4>(g_hRowHi, g_hRowLo, HD, pkPjHi, pkPjLo, 8,
                         ch * 4, 4, 0, g_proj[ch], 128, tid);
        }
    }
}

// ---- f32 VALU 128-col tile GEMM (pre_kernel only) ----
__device__ __forceinline__ void stage128(const float* Wp, int ldw, int wrows,
                                         int co, int pn, float* dst, int tid)
{
    #pragma unroll
    for (int q = 0; q < 2; q++) {
        int s = (q << 9) + tid;
        int r = s >> 5, c4 = s & 31;
        int kr = (pn << 5) + r; if (kr >= wrows) kr = wrows - 1;
        gload_lds16(Wp + kr * ldw + co + (c4 << 2), dst + (s << 2));
    }
}
__device__ __forceinline__ void gemm128(
    const float* AT, const float* Wp, int ldw, int wrows, int co, int np,
    float* Op, int ldo, float* pool, int tid)
{
    int cq = tid & 31, bq = tid >> 5;
    float4 acc0 = {0,0,0,0}, acc1 = {0,0,0,0}, acc2 = {0,0,0,0}, acc3 = {0,0,0,0};
    stage128(Wp, ldw, wrows, co, 0, pool, tid);
    for (int pn = 0; pn < np; pn++) {
        __syncthreads();
        if (pn + 1 < np)
            stage128(Wp, ldw, wrows, co, pn + 1, pool + (((pn + 1) & 1) << 12), tid);
        const float* Ap2 = AT + (pn << 11) + (bq << 2);
        const float* Wcc = pool + ((pn & 1) << 12) + (cq << 2);
        #pragma unroll 8
        for (int k = 0; k < 32; k++) {
            float4 a = *(const float4*)(Ap2 + (k << 6));
            float4 w = *(const float4*)(Wcc + (k << 7));
            acc0.x += a.x*w.x; acc0.y += a.x*w.y; acc0.z += a.x*w.z; acc0.w += a.x*w.w;
            acc1.x += a.y*w.x; acc1.y += a.y*w.y; acc1.z += a.y*w.z; acc1.w += a.y*w.w;
            acc2.x += a.z*w.x; acc2.y += a.z*w.y; acc2.z += a.z*w.z; acc2.w += a.z*w.w;
            acc3.x += a.w*w.x; acc3.y += a.w*w.y; acc3.z += a.w*w.z; acc3.w += a.w*w.w;
        }
    }
    float* op = Op + (bq << 2) * ldo + co + (cq << 2);
    *(float4*)(op)           = acc0;  *(float4*)(op + ldo)     = acc1;
    *(float4*)(op + 2 * ldo) = acc2;  *(float4*)(op + 3 * ldo) = acc3;
}

// ---------------------------------------------------------------------------
// pre: one-time batched x-GEMMs for ALL t. grid 5120 x 512.
// ---------------------------------------------------------------------------
__global__ __launch_bounds__(512, 2) void pre_kernel(
    const float* __restrict__ Wx, const float* __restrict__ Wxh_hy)
{
    __shared__ float pool[8192];
    int u = blockIdx.x, tid = threadIdx.x;
    if (u < 4096) {
        int t = u >> 5, ct = u & 31;
        gemm128(g_xT + t * 192 * 64, Wx, HD4, IN_DIM, ct * 128, 5,
                g_xWxA[t], HD4, pool, tid);
    } else {
        int i = u - 4096, t = i >> 3, ct = i & 7;
        gemm128(g_xT + t * 192 * 64, Wxh_hy, HD, IN_DIM, ct * 128, 5,
                g_gxA[t], HD, pool, tid);
    }
}

// ---------------------------------------------------------------------------
// K2: blocks [0,64): gate-sum -> hh/ch -> z GEMV (1024 thr, 1 b per block).
//     blocks [64,128): proj epilogue + MDN for t-1.
// ---------------------------------------------------------------------------
__global__ __launch_bounds__(1024) void k2_kernel(
    const float* __restrict__ b_hy,
    const float* __restrict__ Wzx, const float* __restrict__ bzx,
    const float* __restrict__ Wzh, const float* __restrict__ bzh,
    const float* __restrict__ Wzb,
    const float* __restrict__ fc_proj_b, float* __restrict__ out, int t)
{
    __shared__ float gsum[1024];
    __shared__ float hhB[256];
    int blk = blockIdx.x, tid = threadIdx.x;
    if (blk < 64) {
        if (t >= NSEQ) return;
        int b = blk, base = b * HD;
        {
            int j = tid;
            float a = b_hy[j] + g_gxA[t][base + j];
            #pragma unroll
            for (int c = 0; c < 8; c++) a += g_gH[c][base + j];
            a += g_ghh[0][base + j] + g_ghh[1][base + j];
            gsum[j] = a;
        }
        __syncthreads();
        if (tid < 256) {
            float gi = gsum[tid],       gf = gsum[256 + tid];
            float gg = gsum[512 + tid], go = gsum[768 + tid];
            float ch = g_ch[b * HY + tid];
            ch = sigf(gf) * ch + sigf(gi) * tanhf(gg);
            float hh = sigf(go) * tanhf(ch);
            g_ch[b * HY + tid] = ch;
            bf16pair(hh, &g_hhRowHi[b * HY + tid], &g_hhRowLo[b * HY + tid]);
            hhB[tid] = hh;
        }
        __syncthreads();
        if (tid < 768) {
            int ten = tid >> 8, oo = tid & 255;
            const float* Wz = (ten == 0) ? Wzx : (ten == 1) ? Wzh : Wzb;
            float acc = (ten == 0) ? bzx[oo] : (ten == 1) ? bzh[oo] : 0.f;
            #pragma unroll 8
            for (int k = 0; k < HY; k++) acc += hhB[k] * Wz[(k << 8) + oo];
            g_z[b * 768 + tid] = acc;
        }
    } else {
        if (t == 0) return;
        int b = blk - 64, tp = t - 1, base7 = b << 7;
        int c = tid;
        if (c < 120) {
            float v = fc_proj_b[c];
            #pragma unroll
            for (int q = 0; q < 8; q++) v += g_proj[q][base7 + c];
            int m = c / 6, r = c - m * 6;
            int oidx = tp * (MM * BB) + m * BB + b;
            if      (r == 0) out[oidx]          = 1.0f;   // size-1 softmax
            else if (r == 1) out[163840 + oidx] = v;
            else if (r == 2) out[327680 + oidx] = v;
            else if (r == 3) out[491520 + oidx] = expf(v);
            else if (r == 4) out[655360 + oidx] = expf(v);
            else             out[819200 + oidx] = tanhf(v);
        } else if (c == 120) {                   // pen-state softmax
            float p0 = fc_proj_b[120], p1 = fc_proj_b[121], p2 = fc_proj_b[122];
            #pragma unroll
            for (int q = 0; q < 8; q++) {
                p0 += g_proj[q][base7 + 120];
                p1 += g_proj[q][base7 + 121];
                p2 += g_proj[q][base7 + 122];
            }
            float mx = fmaxf(p0, fmaxf(p1, p2));
            float e0 = expf(p0 - mx), e1 = expf(p1 - mx), e2 = expf(p2 - mx);
            float s = e0 + e1 + e2;
            int ob = 983040 + tp * (BB * 3) + b * 3;
            out[ob + 0] = e0 / s; out[ob + 1] = e1 / s; out[ob + 2] = e2 / s;
        }
    }
}

// ---------------------------------------------------------------------------
// K3: einsum + combine (8 hWh partials + precomp xWx) + LSTM update.
// grid 256 x 512. Writes h as bf16 hi/lo rows for next KA.
// ---------------------------------------------------------------------------
__global__ __launch_bounds__(512) void k3_kernel(
    const float* __restrict__ Dx, const float* __restrict__ Dh,
    const float* __restrict__ Db, const float* __restrict__ b0w, int t)
{
    __shared__ float zC[6144];
    __shared__ float preC[1024];
    int blk = blockIdx.x, tid = threadIdx.x;
    int bg = blk >> 5, sl = blk & 31;
    int hi0 = sl << 5;
    {
        const float4* src = (const float4*)(g_z + bg * 8 * 768);
        float4* dst = (float4*)zC;
        for (int i = tid; i < 1536; i += 512) dst[i] = src[i];
    }
    __syncthreads();
    int hi_l = tid & 31, gq = (tid >> 5) & 3, b4 = tid >> 7;
    int hi = hi0 + hi_l;
    const float* dxp = Dx + gq * 64 * HD + hi;
    const float* dhp = Dh + gq * 64 * HD + hi;
    const float* dbp = Db + gq * 64 * HD + hi;
    const float* z0 = zC + b4 * 768;
    const float* z1 = zC + (b4 + 4) * 768;
    int zo = gq << 6;
    float ax0 = 0.f, ah0 = 0.f, ab0 = 0.f, ax1 = 0.f, ah1 = 0.f, ab1 = 0.f;
    #pragma unroll 4
    for (int f = 0; f < FF; f++) {
        float dx = dxp[f * HD], dh = dhp[f * HD], db = dbp[f * HD];
        ax0 += z0[zo + f] * dx; ah0 += z0[256 + zo + f] * dh;
        ab0 += z0[512 + zo + f] * db;
        ax1 += z1[zo + f] * dx; ah1 += z1[256 + zo + f] * dh;
        ab1 += z1[512 + zo + f] * db;
    }
    int idx = (gq << 10) + hi;
    int b0i = (bg << 3) + b4, b1i = b0i + 4;
    float hw0 = 0.f, hw1 = 0.f;
    #pragma unroll
    for (int q = 0; q < 8; q++) {
        hw0 += g_hWh[q][b0i * HD4 + idx];
        hw1 += g_hWh[q][b1i * HD4 + idx];
    }
    float xw0 = g_xWxA[t][b0i * HD4 + idx], xw1 = g_xWxA[t][b1i * HD4 + idx];
    float bw = b0w[idx];
    float pre0 = ax0 * xw0 + ah0 * hw0 + ab0 + bw;
    float pre1 = ax1 * xw1 + ah1 * hw1 + ab1 + bw;
    preC[((b4 << 2) + gq) * 32 + hi_l]       = pre0;
    preC[(((b4 + 4) << 2) + gq) * 32 + hi_l] = pre1;
    __syncthreads();
    if (tid < 256) {
        int bi = tid >> 5, hl = tid & 31;
        int b8 = (bg << 3) + bi, ha = b8 * HD + hi0 + hl;
        float pi = preC[((bi << 2) + 0) * 32 + hl];
        float pf = preC[((bi << 2) + 1) * 32 + hl];
        float pg = preC[((bi << 2) + 2) * 32 + hl];
        float po = preC[((bi << 2) + 3) * 32 + hl];
        float cv = g_c[ha];
        float nc = sigf(pf) * cv + sigf(pi) * tanhf(pg);
        float nh = sigf(po) * tanhf(nc);
        g_c[ha] = nc;
        bf16pair(nh, &g_hRowHi[ha], &g_hRowLo[ha]);
    }
}

// ---------------------------------------------------------------------------
extern "C" void kernel_launch(void* const* d_in, const int* in_sizes, int n_in,
                              void* d_out, int out_size, void* d_ws, size_t ws_size,
                              hipStream_t stream)
{
    const float* z         = (const float*)d_in[0];
    const float* strokes   = (const float*)d_in[1];
    const float* fc_in_w   = (const float*)d_in[2];
    const float* fc_in_b   = (const float*)d_in[3];
    const float* fc_proj_w = (const float*)d_in[4];
    const float* fc_proj_b = (const float*)d_in[5];
    const float* Wx        = (const float*)d_in[6];
    const float* Wh        = (const float*)d_in[7];
    const float* b0w       = (const float*)d_in[8];
    const float* Wxh_hy    = (const float*)d_in[9];
    const float* Whh_hy    = (const float*)d_in[10];
    const float* b_hy      = (const float*)d_in[11];
    const float* Wzx       = (const float*)d_in[12];
    const float* bzx       = (const float*)d_in[13];
    const float* Wzh       = (const float*)d_in[14];
    const float* bzh       = (const float*)d_in[15];
    const float* Wzb       = (const float*)d_in[16];
    const float* Dx        = (const float*)d_in[17];
    const float* Dh        = (const float*)d_in[18];
    const float* Db        = (const float*)d_in[19];
    (void)d_ws; (void)ws_size; (void)in_sizes; (void)n_in; (void)out_size;
    float* out = (float*)d_out;

    init_kernel<<<64, 256, 0, stream>>>(z, fc_in_w, fc_in_b);
    xt_kernel<<<128, 256, 0, stream>>>(strokes);
    pack_kernel<<<11008, 512, 0, stream>>>(Wh, Wxh_hy, Whh_hy, fc_proj_w);
    pre_kernel<<<5120, 512, 0, stream>>>(Wx, Wxh_hy);
    for (int t = 0; t < NSEQ; t++) {
        ka_kernel<<<176, 512, 0, stream>>>(t);
        k2_kernel<<<128, 1024, 0, stream>>>(b_hy, Wzx, bzx, Wzh, bzh, Wzb,
                                            fc_proj_b, out, t);
        k3_kernel<<<256, 512, 0, stream>>>(Dx, Dh, Db, b0w, t);
    }
    // tail: proj of h_127 + its epilogue
    ka_kernel<<<176, 512, 0, stream>>>(NSEQ);
    k2_kernel<<<128, 1024, 0, stream>>>(b_hy, Wzx, bzx, Wzh, bzh, Wzb,
                                        fc_proj_b, out, NSEQ);
}